// Round 15
// baseline (318.108 us; speedup 1.0000x reference)
//
#include <hip/hip_runtime.h>
#include <hip/hip_bf16.h>

typedef __hip_bfloat16 bf16;
typedef short s8v __attribute__((ext_vector_type(8)));   // 8 bf16 in 4 VGPRs
typedef float f4v __attribute__((ext_vector_type(4)));   // MFMA 16x16 C/D frag
typedef float v2f __attribute__((ext_vector_type(2)));   // packed f32 pair (v_pk_add_f32)

__device__ __forceinline__ short f2b(float f) {
  bf16 h = __float2bfloat16(f);
  return *reinterpret_cast<short*>(&h);
}
// accumulate 2 bf16 (one dword, memory order) into packed f32 pair
__device__ __forceinline__ void bf2_acc(int d, v2f& a) {
  v2f u;
  u.x = __int_as_float(d << 16);
  u.y = __int_as_float(d & 0xFFFF0000);
  a += u;   // single v_pk_add_f32
}

#define BSHIFT 8        // 256 dest nodes per bucket
#define BNODES 256
#define CHUNK 4096      // edges per chunk
#define SORT_CAP 12288  // bucket-sort LDS capacity (48 KB); mean bucket = 8192
#define TSHIFT 15       // source tile = 32K rows = 4 MB of g1 (fits per-XCD L2)
#define ACAP 768        // adj LDS stage cap per 8-dest gagg2 block

// ---- weight prep + btot zero-init (first kernel in stream) ----
__global__ __launch_bounds__(256) void k_prepW(const float* __restrict__ W1,
                                               const float* __restrict__ W2,
                                               short* __restrict__ Wt1,
                                               short* __restrict__ Wt2,
                                               int* __restrict__ btot, int nbuck) {
  int t = blockIdx.x * 256 + threadIdx.x;
  if (t < 128 * 64) { int k = t >> 6, c = t & 63; Wt1[c * 128 + k] = f2b(W1[t]); }
  if (t < 64 * 32)  { int k = t >> 5, c = t & 31; Wt2[c * 64 + k] = f2b(W2[t]); }
  if (t < nbuck)    btot[t] = 0;
}

// ---- phase 1: per-chunk bucket histogram -> ONE global atomicAdd per bucket ----
// (r21: replaces k_hist+chist+k_scanbuck; bucket-internal order becomes
//  nondeterministic, which bucketsort's atomic cursors already were)
__global__ __launch_bounds__(256) void k_count(const int* __restrict__ col, int E,
                                               int nbuck, int* __restrict__ btot) {
  __shared__ int hist[512];
  int t = threadIdx.x;
  hist[t] = 0; hist[t + 256] = 0;
  __syncthreads();
  int e0 = blockIdx.x * CHUNK;
#pragma unroll
  for (int i = 0; i < 16; i++) {
    int e = e0 + i * 256 + t;
    if (e < E) atomicAdd(&hist[col[e] >> BSHIFT], 1);
  }
  __syncthreads();
  for (int b = t; b < nbuck; b += 256)
    if (hist[b]) atomicAdd(&btot[b], hist[b]);
}

// ---- phase 2: scan bucket totals -> bbase, gcur (atomic cursors), row_start[n] ----
__global__ __launch_bounds__(512) void k_scanbase(const int* __restrict__ btot, int nbuck,
                                                  int* __restrict__ bbase,
                                                  int* __restrict__ gcur,
                                                  int* __restrict__ row_start, int n) {
  __shared__ int sm[512];
  int t = threadIdx.x;
  int v = (t < nbuck) ? btot[t] : 0;
  sm[t] = v;
  __syncthreads();
  for (int d = 1; d < 512; d <<= 1) {   // Hillis-Steele inclusive
    int x = (t >= d) ? sm[t - d] : 0;
    __syncthreads();
    sm[t] += x;
    __syncthreads();
  }
  if (t < nbuck) {
    int e = sm[t] - v;                  // exclusive prefix
    bbase[t] = e;
    gcur[t] = e;
  }
  if (t == nbuck - 1) {
    bbase[nbuck] = sm[t];
    row_start[n] = sm[t];  // == E
  }
}

// ---- phase 3: grouped scatter into bucket-grouped adjTmp via atomic cursors ----
// adjTmp entry: r | (c_low << 17)
__global__ __launch_bounds__(256) void k_binpass(const int* __restrict__ row,
                                                 const int* __restrict__ col, int E,
                                                 int nbuck,
                                                 int* __restrict__ gcur,
                                                 int* __restrict__ adjTmp) {
  __shared__ int hist[512];
  __shared__ int base[512];
  __shared__ int lcur[512];
  __shared__ int gbase[512];
  __shared__ int psum[256];
  __shared__ int stage[CHUNK];
  __shared__ unsigned short sbkt[CHUNK];
  __shared__ int s_total;
  int t = threadIdx.x;
  int e0 = blockIdx.x * CHUNK;

  hist[t] = 0; hist[t + 256] = 0;
  __syncthreads();

  int pk[16], bk[16];
#pragma unroll
  for (int i = 0; i < 16; i++) {
    int e = e0 + i * 256 + t;
    if (e < E) {
      int c = col[e];
      int r = row[e];
      bk[i] = c >> BSHIFT;
      pk[i] = r | ((c & (BNODES - 1)) << 17);
      atomicAdd(&hist[bk[i]], 1);
    } else bk[i] = -1;
  }
  __syncthreads();
  int a0 = hist[2 * t], a1 = hist[2 * t + 1];
  psum[t] = a0 + a1;
  __syncthreads();
  for (int d = 1; d < 256; d <<= 1) {
    int v = (t >= d) ? psum[t - d] : 0;
    __syncthreads();
    psum[t] += v;
    __syncthreads();
  }
  int pref = (t == 0) ? 0 : psum[t - 1];
  base[2 * t] = pref;          lcur[2 * t] = pref;
  base[2 * t + 1] = pref + a0; lcur[2 * t + 1] = pref + a0;
  if (t == 255) s_total = psum[255];
  // reserve this block's range in each non-empty bucket (one atomic per bucket)
  for (int b = t; b < nbuck; b += 256)
    gbase[b] = hist[b] ? atomicAdd(&gcur[b], hist[b]) : 0;
  __syncthreads();
#pragma unroll
  for (int i = 0; i < 16; i++) {
    if (bk[i] >= 0) {
      int pos = atomicAdd(&lcur[bk[i]], 1);
      stage[pos] = pk[i];
      sbkt[pos] = (unsigned short)bk[i];
    }
  }
  __syncthreads();
  int total = s_total;
  for (int i = t; i < total; i += 256) {
    int b = sbkt[i];
    adjTmp[gbase[b] + (i - base[b])] = stage[i];
  }
}

// ---- phase 4: per-bucket sort, key = (c_low, src_tile); emits dinv, row_start,
//      adj sorted by dest; entries premultiplied r<<7 (byte offset of 128B row) ----
__global__ __launch_bounds__(256) void k_bucketsort(const int* __restrict__ bbase,
                                                    const int* __restrict__ adjTmp,
                                                    int* __restrict__ adj,
                                                    int* __restrict__ row_start,
                                                    float* __restrict__ dinv, int n) {
  __shared__ int cnt[1024];
  __shared__ int sc[256];
  __shared__ int cur[1024];
  __shared__ int stage[SORT_CAP];
  int b = blockIdx.x, t = threadIdx.x;
  int node_base = b << BSHIFT;
  int nnode = min(BNODES, n - node_base);
  int seg_base = bbase[b];
  int cntE = bbase[b + 1] - seg_base;
  cnt[t] = 0; cnt[t + 256] = 0; cnt[t + 512] = 0; cnt[t + 768] = 0;
  __syncthreads();
  for (int i = t; i < cntE; i += 256) {
    int p = adjTmp[seg_base + i];
    int key = (((p >> 17) & 255) << 2) | ((p >> TSHIFT) & 3);
    atomicAdd(&cnt[key], 1);
  }
  __syncthreads();
  int c0 = cnt[4 * t], c1 = cnt[4 * t + 1], c2 = cnt[4 * t + 2], c3 = cnt[4 * t + 3];
  int myc = c0 + c1 + c2 + c3;        // node degree
  sc[t] = myc;
  __syncthreads();
  for (int d = 1; d < 256; d <<= 1) {
    int x = (t >= d) ? sc[t - d] : 0;
    __syncthreads();
    sc[t] += x;
    __syncthreads();
  }
  int excl = (t == 0) ? 0 : sc[t - 1];
  cur[4 * t] = excl;
  cur[4 * t + 1] = excl + c0;
  cur[4 * t + 2] = excl + c0 + c1;
  cur[4 * t + 3] = excl + c0 + c1 + c2;
  if (t < nnode) {
    row_start[node_base + t] = seg_base + excl;
    dinv[node_base + t] = rsqrtf((float)myc + 1.0f);  // +1 = self-loop
  }
  __syncthreads();
  if (cntE <= SORT_CAP) {
    for (int i = t; i < cntE; i += 256) {
      int p = adjTmp[seg_base + i];
      int key = (((p >> 17) & 255) << 2) | ((p >> TSHIFT) & 3);
      int pos = atomicAdd(&cur[key], 1);
      stage[pos] = (p & 0x1FFFF) << 7;
    }
    __syncthreads();
    for (int i = t; i < cntE; i += 256) adj[seg_base + i] = stage[i];
  } else {
    // fallback (statistically never)
    for (int i = t; i < cntE; i += 256) {
      int p = adjTmp[seg_base + i];
      int key = (((p >> 17) & 255) << 2) | ((p >> TSHIFT) & 3);
      int pos = atomicAdd(&cur[key], 1);
      adj[seg_base + pos] = (p & 0x1FFFF) << 7;
    }
  }
}

// ---- MFMA gemm1: g1[n,64] = dinv[r]*(x[n,128] @ W1[128,64]), bf16 out ----
__global__ __launch_bounds__(256) void k_gemm1(const float* __restrict__ x,
                                               const short* __restrict__ Wt,  // [64][128] bf16
                                               const float* __restrict__ dinv,
                                               bf16* __restrict__ g1, int n) {
  int wave = threadIdx.x >> 6;
  int lane = threadIdx.x & 63;
  int m = lane & 15;
  int quad = lane >> 4;
  int r = blockIdx.x * 64 + wave * 16 + m;

  s8v afr[4];
  if (r < n) {
    const float* ap = x + (size_t)r * 128 + quad * 8;
#pragma unroll
    for (int kc = 0; kc < 4; kc++) {
      float4 u = *(const float4*)(ap + kc * 32);
      float4 v = *(const float4*)(ap + kc * 32 + 4);
      s8v a;
      a[0] = f2b(u.x); a[1] = f2b(u.y); a[2] = f2b(u.z); a[3] = f2b(u.w);
      a[4] = f2b(v.x); a[5] = f2b(v.y); a[6] = f2b(v.z); a[7] = f2b(v.w);
      afr[kc] = a;
    }
  } else {
#pragma unroll
    for (int kc = 0; kc < 4; kc++) afr[kc] = (s8v)(short)0;
  }

  const short* wp = Wt + (size_t)m * 128 + quad * 8;
  s8v bfr[4][4];
#pragma unroll
  for (int nt = 0; nt < 4; nt++)
#pragma unroll
    for (int kc = 0; kc < 4; kc++)
      bfr[nt][kc] = *(const s8v*)(wp + nt * 16 * 128 + kc * 32);

  f4v acc[4] = {f4v{0,0,0,0}, f4v{0,0,0,0}, f4v{0,0,0,0}, f4v{0,0,0,0}};
#pragma unroll
  for (int kc = 0; kc < 4; kc++)
#pragma unroll
    for (int nt = 0; nt < 4; nt++)
      acc[nt] = __builtin_amdgcn_mfma_f32_16x16x32_bf16(afr[kc], bfr[nt][kc], acc[nt], 0, 0, 0);

  int rbase = blockIdx.x * 64 + wave * 16 + quad * 4;
#pragma unroll
  for (int reg = 0; reg < 4; reg++) {
    int rr = rbase + reg;
    if (rr < n) {
      float dv = dinv[rr];
#pragma unroll
      for (int nt = 0; nt < 4; nt++)
        g1[(size_t)rr * 64 + nt * 16 + m] = __float2bfloat16(acc[nt][reg] * dv);
    }
  }
}

// ---- MFMA gemm2: g2[n,32] = dinv[r]*(z1b[n,64] @ W2[64,32]), bf16 out ----
__global__ __launch_bounds__(256) void k_gemm2(const bf16* __restrict__ z1b,
                                               const short* __restrict__ Wt,  // [32][64] bf16
                                               const float* __restrict__ dinv,
                                               short* __restrict__ g2, int n) {
  int wave = threadIdx.x >> 6;
  int lane = threadIdx.x & 63;
  int m = lane & 15;
  int quad = lane >> 4;
  int r = blockIdx.x * 64 + wave * 16 + m;

  s8v afr[2];
  if (r < n) {
    const short* ap = (const short*)z1b + (size_t)r * 64 + quad * 8;
#pragma unroll
    for (int kc = 0; kc < 2; kc++) afr[kc] = *(const s8v*)(ap + kc * 32);
  } else {
#pragma unroll
    for (int kc = 0; kc < 2; kc++) afr[kc] = (s8v)(short)0;
  }

  const short* wp = Wt + (size_t)m * 64 + quad * 8;
  s8v bfr[2][2];
#pragma unroll
  for (int nt = 0; nt < 2; nt++)
#pragma unroll
    for (int kc = 0; kc < 2; kc++)
      bfr[nt][kc] = *(const s8v*)(wp + nt * 16 * 64 + kc * 32);

  f4v acc[2] = {f4v{0,0,0,0}, f4v{0,0,0,0}};
#pragma unroll
  for (int kc = 0; kc < 2; kc++)
#pragma unroll
    for (int nt = 0; nt < 2; nt++)
      acc[nt] = __builtin_amdgcn_mfma_f32_16x16x32_bf16(afr[kc], bfr[nt][kc], acc[nt], 0, 0, 0);

  int rbase = blockIdx.x * 64 + wave * 16 + quad * 4;
#pragma unroll
  for (int reg = 0; reg < 4; reg++) {
    int rr = rbase + reg;
    if (rr < n) {
      float dv = dinv[rr];
#pragma unroll
      for (int nt = 0; nt < 2; nt++)
        g2[(size_t)rr * 32 + nt * 16 + m] = f2b(acc[nt][reg] * dv);
    }
  }
}

// ---- layer-1 aggregate: r14 (verified): 1 wave per 2 dests, dual-row
//      front-loaded pipeline, plain loads/stores ----
__global__ __launch_bounds__(256) void k_gagg1(const int* __restrict__ row_start,
                                               const int* __restrict__ adj,
                                               const float* __restrict__ dinv,
                                               const short* __restrict__ g,   // g1 bf16 [n][64]
                                               const float* __restrict__ bias,
                                               short* __restrict__ z, int n, int E) {
  int wv = __builtin_amdgcn_readfirstlane((int)threadIdx.x) >> 6;
  int lane = threadIdx.x & 63;
  int grp = lane >> 3;     // 0..7: edge slot
  int fl = lane & 7;       // feature slice: shorts fl*8..fl*8+7 (16 B)
  int c0 = (blockIdx.x * 4 + wv) * 2;
  if (c0 >= n) return;
  int c1 = c0 + 1;
  bool hasB = (c1 < n);
  int sA = row_start[c0];
  int eA = row_start[c1];
  int eB = hasB ? row_start[c1 + 1] : eA;
  int sB = eA;
  const char* gb = (const char*)g;
  int fo = fl * 16;        // byte offset of feature slice within a 128 B row

  int mA = max(min(eA - 1, E - 1), 0);
  int mB = max(min(eB - 1, E - 1), 0);

  int vA0 = adj[min(sA + grp, mA)];
  int vA1 = adj[min(sA + 8 + grp, mA)];
  int vA2 = adj[min(sA + 16 + grp, mA)];
  int vA3 = adj[min(sA + 24 + grp, mA)];
  int vB0 = adj[min(sB + grp, mB)];
  int vB1 = adj[min(sB + 8 + grp, mB)];
  int vB2 = adj[min(sB + 16 + grp, mB)];
  int vB3 = adj[min(sB + 24 + grp, mB)];
  int4 p0 = *(const int4*)(gb + (unsigned)(vA0 + fo));
  int4 p1 = *(const int4*)(gb + (unsigned)(vA1 + fo));
  int4 p2 = *(const int4*)(gb + (unsigned)(vA2 + fo));
  int4 p3 = *(const int4*)(gb + (unsigned)(vA3 + fo));
  int4 q0 = *(const int4*)(gb + (unsigned)(vB0 + fo));
  int4 q1 = *(const int4*)(gb + (unsigned)(vB1 + fo));
  int4 q2 = *(const int4*)(gb + (unsigned)(vB2 + fo));
  int4 q3 = *(const int4*)(gb + (unsigned)(vB3 + fo));

  v2f a0 = {0.f, 0.f}, a1 = {0.f, 0.f}, a2 = {0.f, 0.f}, a3 = {0.f, 0.f};

  auto rest_row = [&](int j, int end) {
    for (; j + 32 <= end; j += 32) {
#pragma unroll
      for (int u = 0; u < 4; u++) {
        int voff = adj[j + u * 8 + grp];
        int4 pk = *(const int4*)(gb + (unsigned)(voff + fo));
        bf2_acc(pk.x, a0); bf2_acc(pk.y, a1); bf2_acc(pk.z, a2); bf2_acc(pk.w, a3);
      }
    }
    if (j < end) {
      int m = end - 1;
      int x0 = adj[min(j + grp, m)];
      int x1 = adj[min(j + 8 + grp, m)];
      int x2 = adj[min(j + 16 + grp, m)];
      int x3 = adj[min(j + 24 + grp, m)];
      int4 t0 = *(const int4*)(gb + (unsigned)(x0 + fo));
      int4 t1 = *(const int4*)(gb + (unsigned)(x1 + fo));
      int4 t2 = *(const int4*)(gb + (unsigned)(x2 + fo));
      int4 t3 = *(const int4*)(gb + (unsigned)(x3 + fo));
      if (j + grp < end)      { bf2_acc(t0.x, a0); bf2_acc(t0.y, a1); bf2_acc(t0.z, a2); bf2_acc(t0.w, a3); }
      if (j + 8 + grp < end)  { bf2_acc(t1.x, a0); bf2_acc(t1.y, a1); bf2_acc(t1.z, a2); bf2_acc(t1.w, a3); }
      if (j + 16 + grp < end) { bf2_acc(t2.x, a0); bf2_acc(t2.y, a1); bf2_acc(t2.z, a2); bf2_acc(t2.w, a3); }
      if (j + 24 + grp < end) { bf2_acc(t3.x, a0); bf2_acc(t3.y, a1); bf2_acc(t3.z, a2); bf2_acc(t3.w, a3); }
    }
  };

  auto finish = [&](int c) {
#pragma unroll
    for (int s = 8; s <= 32; s <<= 1) {
      a0.x += __shfl_xor(a0.x, s); a0.y += __shfl_xor(a0.y, s);
      a1.x += __shfl_xor(a1.x, s); a1.y += __shfl_xor(a1.y, s);
      a2.x += __shfl_xor(a2.x, s); a2.y += __shfl_xor(a2.y, s);
      a3.x += __shfl_xor(a3.x, s); a3.y += __shfl_xor(a3.y, s);
    }
    if (grp == 0) {
      int4 pk = *(const int4*)(gb + (((unsigned)c << 7) + fo));   // self-loop
      bf2_acc(pk.x, a0); bf2_acc(pk.y, a1);
      bf2_acc(pk.z, a2); bf2_acc(pk.w, a3);
      float d = dinv[c];
      float4 b0 = *(const float4*)(bias + fl * 8);
      float4 b1 = *(const float4*)(bias + fl * 8 + 4);
      float v0 = fmaxf(fmaf(d, a0.x, b0.x), 0.f);
      float v1 = fmaxf(fmaf(d, a0.y, b0.y), 0.f);
      float v2 = fmaxf(fmaf(d, a1.x, b0.z), 0.f);
      float v3 = fmaxf(fmaf(d, a1.y, b0.w), 0.f);
      float v4 = fmaxf(fmaf(d, a2.x, b1.x), 0.f);
      float v5 = fmaxf(fmaf(d, a2.y, b1.y), 0.f);
      float v6 = fmaxf(fmaf(d, a3.x, b1.z), 0.f);
      float v7 = fmaxf(fmaf(d, a3.y, b1.w), 0.f);
      int4 out;
      out.x = (int)(unsigned short)f2b(v0) | ((int)f2b(v1) << 16);
      out.y = (int)(unsigned short)f2b(v2) | ((int)f2b(v3) << 16);
      out.z = (int)(unsigned short)f2b(v4) | ((int)f2b(v5) << 16);
      out.w = (int)(unsigned short)f2b(v6) | ((int)f2b(v7) << 16);
      *(int4*)(z + c * 64 + fl * 8) = out;
    }
  };

  if (sA + grp < eA)      { bf2_acc(p0.x, a0); bf2_acc(p0.y, a1); bf2_acc(p0.z, a2); bf2_acc(p0.w, a3); }
  if (sA + 8 + grp < eA)  { bf2_acc(p1.x, a0); bf2_acc(p1.y, a1); bf2_acc(p1.z, a2); bf2_acc(p1.w, a3); }
  if (sA + 16 + grp < eA) { bf2_acc(p2.x, a0); bf2_acc(p2.y, a1); bf2_acc(p2.z, a2); bf2_acc(p2.w, a3); }
  if (sA + 24 + grp < eA) { bf2_acc(p3.x, a0); bf2_acc(p3.y, a1); bf2_acc(p3.z, a2); bf2_acc(p3.w, a3); }
  rest_row(sA + 32, eA);
  finish(c0);

  if (hasB) {
    a0 = v2f{0.f, 0.f}; a1 = v2f{0.f, 0.f}; a2 = v2f{0.f, 0.f}; a3 = v2f{0.f, 0.f};
    if (sB + grp < eB)      { bf2_acc(q0.x, a0); bf2_acc(q0.y, a1); bf2_acc(q0.z, a2); bf2_acc(q0.w, a3); }
    if (sB + 8 + grp < eB)  { bf2_acc(q1.x, a0); bf2_acc(q1.y, a1); bf2_acc(q1.z, a2); bf2_acc(q1.w, a3); }
    if (sB + 16 + grp < eB) { bf2_acc(q2.x, a0); bf2_acc(q2.y, a1); bf2_acc(q2.z, a2); bf2_acc(q2.w, a3); }
    if (sB + 24 + grp < eB) { bf2_acc(q3.x, a0); bf2_acc(q3.y, a1); bf2_acc(q3.z, a2); bf2_acc(q3.w, a3); }
    rest_row(sB + 32, eB);
    finish(c1);
  }
}

// ---- layer-2 aggregate: r19 LDS-staged adj (verified gain for short rows) ----
__global__ __launch_bounds__(256) void k_gagg2(const int* __restrict__ row_start,
                                               const int* __restrict__ adj,
                                               const float* __restrict__ dinv,
                                               const short* __restrict__ g,   // g2 bf16 [n][32]
                                               const float* __restrict__ bias,
                                               float* __restrict__ z, int n, int E) {
  __shared__ int la[ACAP];
  int t = threadIdx.x;
  int cbase = blockIdx.x * 8;
  int segLo = row_start[cbase];
  int segHi = row_start[min(cbase + 8, n)];
  int len = segHi - segLo;
  bool fits = (len <= ACAP);
  if (fits) {
    for (int i = t; i < len; i += 256) la[i] = adj[segLo + i];
    if (t == 0 && len == 0) la[0] = 0;
  }
  __syncthreads();

  int wv = __builtin_amdgcn_readfirstlane(t) >> 6;
  int lane = t & 63;
  int grp = lane >> 2;     // 0..15: edge slot
  int fl = lane & 3;       // feature slice: shorts fl*8..fl*8+7 (16 B)
  int c0 = cbase + wv * 2;
  if (c0 >= n) return;
  int c1 = c0 + 1;
  bool hasB = (c1 < n);
  int sA = row_start[c0];
  int eA = row_start[c0 + 1];
  int eB = hasB ? row_start[c1 + 1] : eA;
  int sB = eA;
  const char* gb = (const char*)g;
  int fo = fl * 16;        // byte offset within a 64 B row

  int mA = max(min(eA - 1, E - 1), segLo);
  int mB = max(min(eB - 1, E - 1), segLo);

  auto run = [&](auto LD) {
    int vA0 = LD(min(sA + grp, mA));
    int vA1 = LD(min(sA + 16 + grp, mA));
    int vB0 = LD(min(sB + grp, mB));
    int vB1 = LD(min(sB + 16 + grp, mB));
    int4 p0 = *(const int4*)(gb + (unsigned)((vA0 >> 1) + fo));
    int4 p1 = *(const int4*)(gb + (unsigned)((vA1 >> 1) + fo));
    int4 q0 = *(const int4*)(gb + (unsigned)((vB0 >> 1) + fo));
    int4 q1 = *(const int4*)(gb + (unsigned)((vB1 >> 1) + fo));

    v2f a0 = {0.f, 0.f}, a1 = {0.f, 0.f}, a2 = {0.f, 0.f}, a3 = {0.f, 0.f};

    auto rest_row = [&](int j, int end) {
      for (; j + 32 <= end; j += 32) {
#pragma unroll
        for (int u = 0; u < 2; u++) {
          int voff = LD(j + u * 16 + grp) >> 1;   // r << 6
          int4 pk = *(const int4*)(gb + (unsigned)(voff + fo));
          bf2_acc(pk.x, a0); bf2_acc(pk.y, a1); bf2_acc(pk.z, a2); bf2_acc(pk.w, a3);
        }
      }
      if (j < end) {
        int m = end - 1;
        int x0 = LD(min(j + grp, m)) >> 1;
        int x1 = LD(min(j + 16 + grp, m)) >> 1;
        int4 t0 = *(const int4*)(gb + (unsigned)(x0 + fo));
        int4 t1 = *(const int4*)(gb + (unsigned)(x1 + fo));
        if (j + grp < end)      { bf2_acc(t0.x, a0); bf2_acc(t0.y, a1); bf2_acc(t0.z, a2); bf2_acc(t0.w, a3); }
        if (j + 16 + grp < end) { bf2_acc(t1.x, a0); bf2_acc(t1.y, a1); bf2_acc(t1.z, a2); bf2_acc(t1.w, a3); }
      }
    };

    auto finish = [&](int c) {
#pragma unroll
      for (int s = 4; s <= 32; s <<= 1) {
        a0.x += __shfl_xor(a0.x, s); a0.y += __shfl_xor(a0.y, s);
        a1.x += __shfl_xor(a1.x, s); a1.y += __shfl_xor(a1.y, s);
        a2.x += __shfl_xor(a2.x, s); a2.y += __shfl_xor(a2.y, s);
        a3.x += __shfl_xor(a3.x, s); a3.y += __shfl_xor(a3.y, s);
      }
      if (grp == 0) {
        int4 pk = *(const int4*)(gb + (((unsigned)c << 6) + fo));   // self-loop
        bf2_acc(pk.x, a0); bf2_acc(pk.y, a1);
        bf2_acc(pk.z, a2); bf2_acc(pk.w, a3);
        float d = dinv[c];
        float4 b0 = *(const float4*)(bias + fl * 8);
        float4 b1 = *(const float4*)(bias + fl * 8 + 4);
        float4 o0, o1;
        o0.x = fmaf(d, a0.x, b0.x); o0.y = fmaf(d, a0.y, b0.y);
        o0.z = fmaf(d, a1.x, b0.z); o0.w = fmaf(d, a1.y, b0.w);
        o1.x = fmaf(d, a2.x, b1.x); o1.y = fmaf(d, a2.y, b1.y);
        o1.z = fmaf(d, a3.x, b1.z); o1.w = fmaf(d, a3.y, b1.w);
        *(float4*)(z + c * 32 + fl * 8) = o0;
        *(float4*)(z + c * 32 + fl * 8 + 4) = o1;
      }
    };

    if (sA + grp < eA)      { bf2_acc(p0.x, a0); bf2_acc(p0.y, a1); bf2_acc(p0.z, a2); bf2_acc(p0.w, a3); }
    if (sA + 16 + grp < eA) { bf2_acc(p1.x, a0); bf2_acc(p1.y, a1); bf2_acc(p1.z, a2); bf2_acc(p1.w, a3); }
    rest_row(sA + 32, eA);
    finish(c0);

    if (hasB) {
      a0 = v2f{0.f, 0.f}; a1 = v2f{0.f, 0.f}; a2 = v2f{0.f, 0.f}; a3 = v2f{0.f, 0.f};
      if (sB + grp < eB)      { bf2_acc(q0.x, a0); bf2_acc(q0.y, a1); bf2_acc(q0.z, a2); bf2_acc(q0.w, a3); }
      if (sB + 16 + grp < eB) { bf2_acc(q1.x, a0); bf2_acc(q1.y, a1); bf2_acc(q1.z, a2); bf2_acc(q1.w, a3); }
      rest_row(sB + 32, eB);
      finish(c1);
    }
  };

  if (fits) run([&](int i) { return la[i - segLo]; });
  else      run([&](int i) { return adj[i]; });
}

// ---- link decode: half-wave per label edge, shuffle reduce, fp32 out ----
__global__ __launch_bounds__(256) void k_decode(const int* __restrict__ ea,
                                                const int* __restrict__ eb,
                                                const float* __restrict__ z2,
                                                float* __restrict__ out, int EL) {
  int lane = threadIdx.x & 31;
  int e = blockIdx.x * 8 + (threadIdx.x >> 5);
  if (e >= EL) return;
  int a = ea[e], b = eb[e];
  float p = z2[a * 32 + lane] * z2[b * 32 + lane];
  p += __shfl_down(p, 16);
  p += __shfl_down(p, 8);
  p += __shfl_down(p, 4);
  p += __shfl_down(p, 2);
  p += __shfl_down(p, 1);
  if (lane == 0) out[e] = p;
}

extern "C" void kernel_launch(void* const* d_in, const int* in_sizes, int n_in,
                              void* d_out, int out_size, void* d_ws, size_t ws_size,
                              hipStream_t stream) {
  const float* x   = (const float*)d_in[0];
  const float* W1  = (const float*)d_in[1];
  const float* b1  = (const float*)d_in[2];
  const float* W2  = (const float*)d_in[3];
  const float* b2  = (const float*)d_in[4];
  const int*   ei  = (const int*)d_in[5];   // [2,E]: row=ei[0..E), col=ei[E..2E)
  const int*   eli = (const int*)d_in[6];   // [2,EL]

  const int N  = in_sizes[0] / 128;  // 100000
  const int E  = in_sizes[5] / 2;    // 3200000
  const int EL = in_sizes[6] / 2;    // 200000
  const int* row = ei;
  const int* col = ei + E;
  const int NBUCK = (N + BNODES - 1) / BNODES;   // 391
  const int NCHNK = (E + CHUNK - 1) / CHUNK;     // 782

  // workspace (~58 MB)
  char* ws = (char*)d_ws;
  size_t off = 0;
  auto take = [&](size_t bytes) { char* p = ws + off; off += (bytes + 255) & ~(size_t)255; return p; };
  float* dinv      = (float*)take((size_t)N * 4);
  int*   row_start = (int*)take((size_t)(N + 1) * 4);
  int*   btot      = (int*)take((size_t)NBUCK * 4);
  int*   bbase     = (int*)take((size_t)(NBUCK + 1) * 4);
  int*   gcur      = (int*)take((size_t)NBUCK * 4);
  short* Wt1       = (short*)take((size_t)64 * 128 * 2);
  short* Wt2       = (short*)take((size_t)32 * 64 * 2);
  int*   adjTmp    = (int*)take((size_t)E * 4);               // 12.8 MB
  int*   adj       = (int*)take((size_t)E * 4);               // 12.8 MB
  char*  bufH      = take((size_t)N * 64 * 2);                // g1 bf16 / g2 bf16
  short* z1b       = (short*)take((size_t)N * 64 * 2);        // relu'd, bf16
  float* z2        = (float*)take((size_t)N * 32 * 4);
  (void)ws_size; (void)n_in; (void)out_size;

  bf16*  g1 = (bf16*)bufH;
  short* g2 = (short*)bufH;   // aliases g1 (g1 dead when g2 written)

  k_prepW     <<<32, 256, 0, stream>>>(W1, W2, Wt1, Wt2, btot, NBUCK);
  k_count     <<<NCHNK, 256, 0, stream>>>(col, E, NBUCK, btot);
  k_scanbase  <<<1, 512, 0, stream>>>(btot, NBUCK, bbase, gcur, row_start, N);
  k_binpass   <<<NCHNK, 256, 0, stream>>>(row, col, E, NBUCK, gcur, adjTmp);
  k_bucketsort<<<NBUCK, 256, 0, stream>>>(bbase, adjTmp, adj, row_start, dinv, N);

  k_gemm1<<<(N + 63) / 64, 256, 0, stream>>>(x, Wt1, dinv, g1, N);
  k_gagg1<<<(N + 7) / 8, 256, 0, stream>>>(row_start, adj, dinv, (const short*)g1, b1, z1b, N, E);

  k_gemm2<<<(N + 63) / 64, 256, 0, stream>>>((const bf16*)z1b, Wt2, dinv, g2, N);
  k_gagg2<<<(N + 7) / 8, 256, 0, stream>>>(row_start, adj, dinv, g2, b2, z2, N, E);

  k_decode<<<(EL + 7) / 8, 256, 0, stream>>>(eli, eli + EL, z2, (float*)d_out, EL);
}

// Round 17
// 299.083 us; speedup vs baseline: 1.0636x; 1.0636x over previous
//
#include <hip/hip_runtime.h>
#include <hip/hip_bf16.h>

typedef __hip_bfloat16 bf16;
typedef short s8v __attribute__((ext_vector_type(8)));   // 8 bf16 in 4 VGPRs
typedef float f4v __attribute__((ext_vector_type(4)));   // MFMA 16x16 C/D frag
typedef float v2f __attribute__((ext_vector_type(2)));   // packed f32 pair (v_pk_add_f32)

__device__ __forceinline__ short f2b(float f) {
  bf16 h = __float2bfloat16(f);
  return *reinterpret_cast<short*>(&h);
}
// accumulate 2 bf16 (one dword, memory order) into packed f32 pair
__device__ __forceinline__ void bf2_acc(int d, v2f& a) {
  v2f u;
  u.x = __int_as_float(d << 16);
  u.y = __int_as_float(d & 0xFFFF0000);
  a += u;   // single v_pk_add_f32
}

#define BSHIFT 8        // 256 dest nodes per bucket
#define BNODES 256
#define CHUNK 4096      // edges per chunk
#define SORT_CAP 12288  // bucket-sort LDS capacity (48 KB); mean bucket = 8192
#define TSHIFT 15       // source tile = 32K rows = 4 MB of g1 (fits per-XCD L2)
#define ACAP 768        // adj LDS stage cap per 8-dest gagg2 block

// ---- phase 1: per-chunk bucket histogram (LDS atomics only) ----
__global__ __launch_bounds__(256) void k_hist(const int* __restrict__ col, int E,
                                              int nbuck, int* __restrict__ chist) {
  __shared__ int hist[512];
  int t = threadIdx.x;
  hist[t] = 0; hist[t + 256] = 0;
  __syncthreads();
  int e0 = blockIdx.x * CHUNK;
#pragma unroll
  for (int i = 0; i < 16; i++) {
    int e = e0 + i * 256 + t;
    if (e < E) atomicAdd(&hist[col[e] >> BSHIFT], 1);
  }
  __syncthreads();
  int* out = chist + (size_t)blockIdx.x * nbuck;
  for (int b = t; b < nbuck; b += 256) out[b] = hist[b];  // coalesced
}

// ---- phase 2: per-bucket exclusive scan over chunks (in place) ----
__global__ __launch_bounds__(256) void k_scanbuck(int* __restrict__ chist, int nchnk,
                                                  int nbuck, int* __restrict__ btot) {
  __shared__ int sm[256];
  int b = blockIdx.x, t = threadIdx.x;
  int per = (nchnk + 255) / 256;
  int lo = t * per, hi = min(lo + per, nchnk);
  int s = 0;
  for (int i = lo; i < hi; i++) s += chist[(size_t)i * nbuck + b];
  sm[t] = s;
  __syncthreads();
  for (int d = 1; d < 256; d <<= 1) {
    int x = (t >= d) ? sm[t - d] : 0;
    __syncthreads();
    sm[t] += x;
    __syncthreads();
  }
  int off = (t == 0) ? 0 : sm[t - 1];
  for (int i = lo; i < hi; i++) {
    int c = chist[(size_t)i * nbuck + b];
    chist[(size_t)i * nbuck + b] = off;
    off += c;
  }
  if (t == 255) btot[b] = sm[255];
}

// ---- phase 3: scan bucket totals (parallel LDS scan) ----
__global__ __launch_bounds__(512) void k_scanbase(const int* __restrict__ btot, int nbuck,
                                                  int* __restrict__ bbase,
                                                  int* __restrict__ row_start, int n) {
  __shared__ int sm[512];
  int t = threadIdx.x;
  int v = (t < nbuck) ? btot[t] : 0;
  sm[t] = v;
  __syncthreads();
  for (int d = 1; d < 512; d <<= 1) {   // Hillis-Steele inclusive
    int x = (t >= d) ? sm[t - d] : 0;
    __syncthreads();
    sm[t] += x;
    __syncthreads();
  }
  if (t < nbuck) bbase[t] = sm[t] - v;  // exclusive prefix
  if (t == nbuck - 1) {
    bbase[nbuck] = sm[t];
    row_start[n] = sm[t];  // == E
  }
}

// ---- phase 4: grouped scatter into bucket-sorted adjTmp, NO global atomics ----
// adjTmp entry: r | (c_low << 17)
__global__ __launch_bounds__(256) void k_binpass(const int* __restrict__ row,
                                                 const int* __restrict__ col, int E,
                                                 int nbuck,
                                                 const int* __restrict__ bbase,
                                                 const int* __restrict__ chist,
                                                 int* __restrict__ adjTmp) {
  __shared__ int hist[512];
  __shared__ int base[512];
  __shared__ int lcur[512];
  __shared__ int gbase[512];
  __shared__ int psum[256];
  __shared__ int stage[CHUNK];
  __shared__ unsigned short sbkt[CHUNK];
  __shared__ int s_total;
  int t = threadIdx.x;
  int e0 = blockIdx.x * CHUNK;

  hist[t] = 0; hist[t + 256] = 0;
  __syncthreads();

  int pk[16], bk[16];
#pragma unroll
  for (int i = 0; i < 16; i++) {
    int e = e0 + i * 256 + t;
    if (e < E) {
      int c = col[e];
      int r = row[e];
      bk[i] = c >> BSHIFT;
      pk[i] = r | ((c & (BNODES - 1)) << 17);
      atomicAdd(&hist[bk[i]], 1);
    } else bk[i] = -1;
  }
  __syncthreads();
  int a0 = hist[2 * t], a1 = hist[2 * t + 1];
  psum[t] = a0 + a1;
  __syncthreads();
  for (int d = 1; d < 256; d <<= 1) {
    int v = (t >= d) ? psum[t - d] : 0;
    __syncthreads();
    psum[t] += v;
    __syncthreads();
  }
  int pref = (t == 0) ? 0 : psum[t - 1];
  base[2 * t] = pref;          lcur[2 * t] = pref;
  base[2 * t + 1] = pref + a0; lcur[2 * t + 1] = pref + a0;
  if (t == 255) s_total = psum[255];
  const int* coff = chist + (size_t)blockIdx.x * nbuck;
  for (int b = t; b < nbuck; b += 256) gbase[b] = bbase[b] + coff[b];
  __syncthreads();
#pragma unroll
  for (int i = 0; i < 16; i++) {
    if (bk[i] >= 0) {
      int pos = atomicAdd(&lcur[bk[i]], 1);
      stage[pos] = pk[i];
      sbkt[pos] = (unsigned short)bk[i];
    }
  }
  __syncthreads();
  int total = s_total;
  for (int i = t; i < total; i += 256) {
    int b = sbkt[i];
    adjTmp[gbase[b] + (i - base[b])] = stage[i];
  }
}

// ---- phase 5: per-bucket sort, key = (c_low, src_tile); emits dinv, row_start,
//      adj sorted by dest; entries premultiplied r<<7 (byte offset of 128B row) ----
__global__ __launch_bounds__(256) void k_bucketsort(const int* __restrict__ bbase,
                                                    const int* __restrict__ adjTmp,
                                                    int* __restrict__ adj,
                                                    int* __restrict__ row_start,
                                                    float* __restrict__ dinv, int n) {
  __shared__ int cnt[1024];
  __shared__ int sc[256];
  __shared__ int cur[1024];
  __shared__ int stage[SORT_CAP];
  int b = blockIdx.x, t = threadIdx.x;
  int node_base = b << BSHIFT;
  int nnode = min(BNODES, n - node_base);
  int seg_base = bbase[b];
  int cntE = bbase[b + 1] - seg_base;
  cnt[t] = 0; cnt[t + 256] = 0; cnt[t + 512] = 0; cnt[t + 768] = 0;
  __syncthreads();
  for (int i = t; i < cntE; i += 256) {
    int p = adjTmp[seg_base + i];
    int key = (((p >> 17) & 255) << 2) | ((p >> TSHIFT) & 3);
    atomicAdd(&cnt[key], 1);
  }
  __syncthreads();
  int c0 = cnt[4 * t], c1 = cnt[4 * t + 1], c2 = cnt[4 * t + 2], c3 = cnt[4 * t + 3];
  int myc = c0 + c1 + c2 + c3;        // node degree
  sc[t] = myc;
  __syncthreads();
  for (int d = 1; d < 256; d <<= 1) {
    int x = (t >= d) ? sc[t - d] : 0;
    __syncthreads();
    sc[t] += x;
    __syncthreads();
  }
  int excl = (t == 0) ? 0 : sc[t - 1];
  cur[4 * t] = excl;
  cur[4 * t + 1] = excl + c0;
  cur[4 * t + 2] = excl + c0 + c1;
  cur[4 * t + 3] = excl + c0 + c1 + c2;
  if (t < nnode) {
    row_start[node_base + t] = seg_base + excl;
    dinv[node_base + t] = rsqrtf((float)myc + 1.0f);  // +1 = self-loop
  }
  __syncthreads();
  if (cntE <= SORT_CAP) {
    for (int i = t; i < cntE; i += 256) {
      int p = adjTmp[seg_base + i];
      int key = (((p >> 17) & 255) << 2) | ((p >> TSHIFT) & 3);
      int pos = atomicAdd(&cur[key], 1);
      stage[pos] = (p & 0x1FFFF) << 7;
    }
    __syncthreads();
    for (int i = t; i < cntE; i += 256) adj[seg_base + i] = stage[i];
  } else {
    // fallback (statistically never)
    for (int i = t; i < cntE; i += 256) {
      int p = adjTmp[seg_base + i];
      int key = (((p >> 17) & 255) << 2) | ((p >> TSHIFT) & 3);
      int pos = atomicAdd(&cur[key], 1);
      adj[seg_base + pos] = (p & 0x1FFFF) << 7;
    }
  }
}

// ---- weight prep: Wt1[64][128] = W1^T bf16, Wt2[32][64] = W2^T bf16 ----
__global__ __launch_bounds__(256) void k_prepW(const float* __restrict__ W1,
                                               const float* __restrict__ W2,
                                               short* __restrict__ Wt1,
                                               short* __restrict__ Wt2) {
  int t = blockIdx.x * 256 + threadIdx.x;
  if (t < 128 * 64) { int k = t >> 6, c = t & 63; Wt1[c * 128 + k] = f2b(W1[t]); }
  if (t < 64 * 32)  { int k = t >> 5, c = t & 31; Wt2[c * 64 + k] = f2b(W2[t]); }
}

// ---- MFMA gemm1: g1[n,64] = dinv[r]*(x[n,128] @ W1[128,64]), bf16 out ----
__global__ __launch_bounds__(256) void k_gemm1(const float* __restrict__ x,
                                               const short* __restrict__ Wt,  // [64][128] bf16
                                               const float* __restrict__ dinv,
                                               bf16* __restrict__ g1, int n) {
  int wave = threadIdx.x >> 6;
  int lane = threadIdx.x & 63;
  int m = lane & 15;
  int quad = lane >> 4;
  int r = blockIdx.x * 64 + wave * 16 + m;

  s8v afr[4];
  if (r < n) {
    const float* ap = x + (size_t)r * 128 + quad * 8;
#pragma unroll
    for (int kc = 0; kc < 4; kc++) {
      float4 u = *(const float4*)(ap + kc * 32);
      float4 v = *(const float4*)(ap + kc * 32 + 4);
      s8v a;
      a[0] = f2b(u.x); a[1] = f2b(u.y); a[2] = f2b(u.z); a[3] = f2b(u.w);
      a[4] = f2b(v.x); a[5] = f2b(v.y); a[6] = f2b(v.z); a[7] = f2b(v.w);
      afr[kc] = a;
    }
  } else {
#pragma unroll
    for (int kc = 0; kc < 4; kc++) afr[kc] = (s8v)(short)0;
  }

  const short* wp = Wt + (size_t)m * 128 + quad * 8;
  s8v bfr[4][4];
#pragma unroll
  for (int nt = 0; nt < 4; nt++)
#pragma unroll
    for (int kc = 0; kc < 4; kc++)
      bfr[nt][kc] = *(const s8v*)(wp + nt * 16 * 128 + kc * 32);

  f4v acc[4] = {f4v{0,0,0,0}, f4v{0,0,0,0}, f4v{0,0,0,0}, f4v{0,0,0,0}};
#pragma unroll
  for (int kc = 0; kc < 4; kc++)
#pragma unroll
    for (int nt = 0; nt < 4; nt++)
      acc[nt] = __builtin_amdgcn_mfma_f32_16x16x32_bf16(afr[kc], bfr[nt][kc], acc[nt], 0, 0, 0);

  int rbase = blockIdx.x * 64 + wave * 16 + quad * 4;
#pragma unroll
  for (int reg = 0; reg < 4; reg++) {
    int rr = rbase + reg;
    if (rr < n) {
      float dv = dinv[rr];
#pragma unroll
      for (int nt = 0; nt < 4; nt++)
        g1[(size_t)rr * 64 + nt * 16 + m] = __float2bfloat16(acc[nt][reg] * dv);
    }
  }
}

// ---- MFMA gemm2: g2[n,32] = dinv[r]*(z1b[n,64] @ W2[64,32]), bf16 out ----
__global__ __launch_bounds__(256) void k_gemm2(const bf16* __restrict__ z1b,
                                               const short* __restrict__ Wt,  // [32][64] bf16
                                               const float* __restrict__ dinv,
                                               short* __restrict__ g2, int n) {
  int wave = threadIdx.x >> 6;
  int lane = threadIdx.x & 63;
  int m = lane & 15;
  int quad = lane >> 4;
  int r = blockIdx.x * 64 + wave * 16 + m;

  s8v afr[2];
  if (r < n) {
    const short* ap = (const short*)z1b + (size_t)r * 64 + quad * 8;
#pragma unroll
    for (int kc = 0; kc < 2; kc++) afr[kc] = *(const s8v*)(ap + kc * 32);
  } else {
#pragma unroll
    for (int kc = 0; kc < 2; kc++) afr[kc] = (s8v)(short)0;
  }

  const short* wp = Wt + (size_t)m * 64 + quad * 8;
  s8v bfr[2][2];
#pragma unroll
  for (int nt = 0; nt < 2; nt++)
#pragma unroll
    for (int kc = 0; kc < 2; kc++)
      bfr[nt][kc] = *(const s8v*)(wp + nt * 16 * 64 + kc * 32);

  f4v acc[2] = {f4v{0,0,0,0}, f4v{0,0,0,0}};
#pragma unroll
  for (int kc = 0; kc < 2; kc++)
#pragma unroll
    for (int nt = 0; nt < 2; nt++)
      acc[nt] = __builtin_amdgcn_mfma_f32_16x16x32_bf16(afr[kc], bfr[nt][kc], acc[nt], 0, 0, 0);

  int rbase = blockIdx.x * 64 + wave * 16 + quad * 4;
#pragma unroll
  for (int reg = 0; reg < 4; reg++) {
    int rr = rbase + reg;
    if (rr < n) {
      float dv = dinv[rr];
#pragma unroll
      for (int nt = 0; nt < 2; nt++)
        g2[(size_t)rr * 32 + nt * 16 + m] = f2b(acc[nt][reg] * dv);
    }
  }
}

// ---- layer-1 aggregate: r14 plain body (best measured 53.5-53.8 us):
//      1 wave per 2 dests, dual-row front-loaded pipeline ----
__global__ __launch_bounds__(256) void k_gagg1(const int* __restrict__ row_start,
                                               const int* __restrict__ adj,
                                               const float* __restrict__ dinv,
                                               const short* __restrict__ g,   // g1 bf16 [n][64]
                                               const float* __restrict__ bias,
                                               short* __restrict__ z, int n, int E) {
  int wv = __builtin_amdgcn_readfirstlane((int)threadIdx.x) >> 6;
  int lane = threadIdx.x & 63;
  int grp = lane >> 3;     // 0..7: edge slot
  int fl = lane & 7;       // feature slice: shorts fl*8..fl*8+7 (16 B)
  int c0 = (blockIdx.x * 4 + wv) * 2;
  if (c0 >= n) return;
  int c1 = c0 + 1;
  bool hasB = (c1 < n);
  int sA = row_start[c0];
  int eA = row_start[c1];
  int eB = hasB ? row_start[c1 + 1] : eA;
  int sB = eA;
  const char* gb = (const char*)g;
  int fo = fl * 16;        // byte offset of feature slice within a 128 B row

  int mA = max(min(eA - 1, E - 1), 0);
  int mB = max(min(eB - 1, E - 1), 0);

  int vA0 = adj[min(sA + grp, mA)];
  int vA1 = adj[min(sA + 8 + grp, mA)];
  int vA2 = adj[min(sA + 16 + grp, mA)];
  int vA3 = adj[min(sA + 24 + grp, mA)];
  int vB0 = adj[min(sB + grp, mB)];
  int vB1 = adj[min(sB + 8 + grp, mB)];
  int vB2 = adj[min(sB + 16 + grp, mB)];
  int vB3 = adj[min(sB + 24 + grp, mB)];
  int4 p0 = *(const int4*)(gb + (unsigned)(vA0 + fo));
  int4 p1 = *(const int4*)(gb + (unsigned)(vA1 + fo));
  int4 p2 = *(const int4*)(gb + (unsigned)(vA2 + fo));
  int4 p3 = *(const int4*)(gb + (unsigned)(vA3 + fo));
  int4 q0 = *(const int4*)(gb + (unsigned)(vB0 + fo));
  int4 q1 = *(const int4*)(gb + (unsigned)(vB1 + fo));
  int4 q2 = *(const int4*)(gb + (unsigned)(vB2 + fo));
  int4 q3 = *(const int4*)(gb + (unsigned)(vB3 + fo));

  v2f a0 = {0.f, 0.f}, a1 = {0.f, 0.f}, a2 = {0.f, 0.f}, a3 = {0.f, 0.f};

  auto rest_row = [&](int j, int end) {
    for (; j + 32 <= end; j += 32) {
#pragma unroll
      for (int u = 0; u < 4; u++) {
        int voff = adj[j + u * 8 + grp];
        int4 pk = *(const int4*)(gb + (unsigned)(voff + fo));
        bf2_acc(pk.x, a0); bf2_acc(pk.y, a1); bf2_acc(pk.z, a2); bf2_acc(pk.w, a3);
      }
    }
    if (j < end) {
      int m = end - 1;
      int x0 = adj[min(j + grp, m)];
      int x1 = adj[min(j + 8 + grp, m)];
      int x2 = adj[min(j + 16 + grp, m)];
      int x3 = adj[min(j + 24 + grp, m)];
      int4 t0 = *(const int4*)(gb + (unsigned)(x0 + fo));
      int4 t1 = *(const int4*)(gb + (unsigned)(x1 + fo));
      int4 t2 = *(const int4*)(gb + (unsigned)(x2 + fo));
      int4 t3 = *(const int4*)(gb + (unsigned)(x3 + fo));
      if (j + grp < end)      { bf2_acc(t0.x, a0); bf2_acc(t0.y, a1); bf2_acc(t0.z, a2); bf2_acc(t0.w, a3); }
      if (j + 8 + grp < end)  { bf2_acc(t1.x, a0); bf2_acc(t1.y, a1); bf2_acc(t1.z, a2); bf2_acc(t1.w, a3); }
      if (j + 16 + grp < end) { bf2_acc(t2.x, a0); bf2_acc(t2.y, a1); bf2_acc(t2.z, a2); bf2_acc(t2.w, a3); }
      if (j + 24 + grp < end) { bf2_acc(t3.x, a0); bf2_acc(t3.y, a1); bf2_acc(t3.z, a2); bf2_acc(t3.w, a3); }
    }
  };

  auto finish = [&](int c) {
#pragma unroll
    for (int s = 8; s <= 32; s <<= 1) {
      a0.x += __shfl_xor(a0.x, s); a0.y += __shfl_xor(a0.y, s);
      a1.x += __shfl_xor(a1.x, s); a1.y += __shfl_xor(a1.y, s);
      a2.x += __shfl_xor(a2.x, s); a2.y += __shfl_xor(a2.y, s);
      a3.x += __shfl_xor(a3.x, s); a3.y += __shfl_xor(a3.y, s);
    }
    if (grp == 0) {
      int4 pk = *(const int4*)(gb + (((unsigned)c << 7) + fo));   // self-loop
      bf2_acc(pk.x, a0); bf2_acc(pk.y, a1);
      bf2_acc(pk.z, a2); bf2_acc(pk.w, a3);
      float d = dinv[c];
      float4 b0 = *(const float4*)(bias + fl * 8);
      float4 b1 = *(const float4*)(bias + fl * 8 + 4);
      float v0 = fmaxf(fmaf(d, a0.x, b0.x), 0.f);
      float v1 = fmaxf(fmaf(d, a0.y, b0.y), 0.f);
      float v2 = fmaxf(fmaf(d, a1.x, b0.z), 0.f);
      float v3 = fmaxf(fmaf(d, a1.y, b0.w), 0.f);
      float v4 = fmaxf(fmaf(d, a2.x, b1.x), 0.f);
      float v5 = fmaxf(fmaf(d, a2.y, b1.y), 0.f);
      float v6 = fmaxf(fmaf(d, a3.x, b1.z), 0.f);
      float v7 = fmaxf(fmaf(d, a3.y, b1.w), 0.f);
      int4 out;
      out.x = (int)(unsigned short)f2b(v0) | ((int)f2b(v1) << 16);
      out.y = (int)(unsigned short)f2b(v2) | ((int)f2b(v3) << 16);
      out.z = (int)(unsigned short)f2b(v4) | ((int)f2b(v5) << 16);
      out.w = (int)(unsigned short)f2b(v6) | ((int)f2b(v7) << 16);
      *(int4*)(z + c * 64 + fl * 8) = out;
    }
  };

  if (sA + grp < eA)      { bf2_acc(p0.x, a0); bf2_acc(p0.y, a1); bf2_acc(p0.z, a2); bf2_acc(p0.w, a3); }
  if (sA + 8 + grp < eA)  { bf2_acc(p1.x, a0); bf2_acc(p1.y, a1); bf2_acc(p1.z, a2); bf2_acc(p1.w, a3); }
  if (sA + 16 + grp < eA) { bf2_acc(p2.x, a0); bf2_acc(p2.y, a1); bf2_acc(p2.z, a2); bf2_acc(p2.w, a3); }
  if (sA + 24 + grp < eA) { bf2_acc(p3.x, a0); bf2_acc(p3.y, a1); bf2_acc(p3.z, a2); bf2_acc(p3.w, a3); }
  rest_row(sA + 32, eA);
  finish(c0);

  if (hasB) {
    a0 = v2f{0.f, 0.f}; a1 = v2f{0.f, 0.f}; a2 = v2f{0.f, 0.f}; a3 = v2f{0.f, 0.f};
    if (sB + grp < eB)      { bf2_acc(q0.x, a0); bf2_acc(q0.y, a1); bf2_acc(q0.z, a2); bf2_acc(q0.w, a3); }
    if (sB + 8 + grp < eB)  { bf2_acc(q1.x, a0); bf2_acc(q1.y, a1); bf2_acc(q1.z, a2); bf2_acc(q1.w, a3); }
    if (sB + 16 + grp < eB) { bf2_acc(q2.x, a0); bf2_acc(q2.y, a1); bf2_acc(q2.z, a2); bf2_acc(q2.w, a3); }
    if (sB + 24 + grp < eB) { bf2_acc(q3.x, a0); bf2_acc(q3.y, a1); bf2_acc(q3.z, a2); bf2_acc(q3.w, a3); }
    rest_row(sB + 32, eB);
    finish(c1);
  }
}

// ---- layer-2 aggregate: r19 LDS-staged adj (best round-13 combination) ----
__global__ __launch_bounds__(256) void k_gagg2(const int* __restrict__ row_start,
                                               const int* __restrict__ adj,
                                               const float* __restrict__ dinv,
                                               const short* __restrict__ g,   // g2 bf16 [n][32]
                                               const float* __restrict__ bias,
                                               float* __restrict__ z, int n, int E) {
  __shared__ int la[ACAP];
  int t = threadIdx.x;
  int cbase = blockIdx.x * 8;
  int segLo = row_start[cbase];
  int segHi = row_start[min(cbase + 8, n)];
  int len = segHi - segLo;
  bool fits = (len <= ACAP);
  if (fits) {
    for (int i = t; i < len; i += 256) la[i] = adj[segLo + i];
    if (t == 0 && len == 0) la[0] = 0;
  }
  __syncthreads();

  int wv = __builtin_amdgcn_readfirstlane(t) >> 6;
  int lane = t & 63;
  int grp = lane >> 2;     // 0..15: edge slot
  int fl = lane & 3;       // feature slice: shorts fl*8..fl*8+7 (16 B)
  int c0 = cbase + wv * 2;
  if (c0 >= n) return;
  int c1 = c0 + 1;
  bool hasB = (c1 < n);
  int sA = row_start[c0];
  int eA = row_start[c0 + 1];
  int eB = hasB ? row_start[c1 + 1] : eA;
  int sB = eA;
  const char* gb = (const char*)g;
  int fo = fl * 16;        // byte offset within a 64 B row

  int mA = max(min(eA - 1, E - 1), segLo);
  int mB = max(min(eB - 1, E - 1), segLo);

  auto run = [&](auto LD) {
    int vA0 = LD(min(sA + grp, mA));
    int vA1 = LD(min(sA + 16 + grp, mA));
    int vB0 = LD(min(sB + grp, mB));
    int vB1 = LD(min(sB + 16 + grp, mB));
    int4 p0 = *(const int4*)(gb + (unsigned)((vA0 >> 1) + fo));
    int4 p1 = *(const int4*)(gb + (unsigned)((vA1 >> 1) + fo));
    int4 q0 = *(const int4*)(gb + (unsigned)((vB0 >> 1) + fo));
    int4 q1 = *(const int4*)(gb + (unsigned)((vB1 >> 1) + fo));

    v2f a0 = {0.f, 0.f}, a1 = {0.f, 0.f}, a2 = {0.f, 0.f}, a3 = {0.f, 0.f};

    auto rest_row = [&](int j, int end) {
      for (; j + 32 <= end; j += 32) {
#pragma unroll
        for (int u = 0; u < 2; u++) {
          int voff = LD(j + u * 16 + grp) >> 1;   // r << 6
          int4 pk = *(const int4*)(gb + (unsigned)(voff + fo));
          bf2_acc(pk.x, a0); bf2_acc(pk.y, a1); bf2_acc(pk.z, a2); bf2_acc(pk.w, a3);
        }
      }
      if (j < end) {
        int m = end - 1;
        int x0 = LD(min(j + grp, m)) >> 1;
        int x1 = LD(min(j + 16 + grp, m)) >> 1;
        int4 t0 = *(const int4*)(gb + (unsigned)(x0 + fo));
        int4 t1 = *(const int4*)(gb + (unsigned)(x1 + fo));
        if (j + grp < end)      { bf2_acc(t0.x, a0); bf2_acc(t0.y, a1); bf2_acc(t0.z, a2); bf2_acc(t0.w, a3); }
        if (j + 16 + grp < end) { bf2_acc(t1.x, a0); bf2_acc(t1.y, a1); bf2_acc(t1.z, a2); bf2_acc(t1.w, a3); }
      }
    };

    auto finish = [&](int c) {
#pragma unroll
      for (int s = 4; s <= 32; s <<= 1) {
        a0.x += __shfl_xor(a0.x, s); a0.y += __shfl_xor(a0.y, s);
        a1.x += __shfl_xor(a1.x, s); a1.y += __shfl_xor(a1.y, s);
        a2.x += __shfl_xor(a2.x, s); a2.y += __shfl_xor(a2.y, s);
        a3.x += __shfl_xor(a3.x, s); a3.y += __shfl_xor(a3.y, s);
      }
      if (grp == 0) {
        int4 pk = *(const int4*)(gb + (((unsigned)c << 6) + fo));   // self-loop
        bf2_acc(pk.x, a0); bf2_acc(pk.y, a1);
        bf2_acc(pk.z, a2); bf2_acc(pk.w, a3);
        float d = dinv[c];
        float4 b0 = *(const float4*)(bias + fl * 8);
        float4 b1 = *(const float4*)(bias + fl * 8 + 4);
        float4 o0, o1;
        o0.x = fmaf(d, a0.x, b0.x); o0.y = fmaf(d, a0.y, b0.y);
        o0.z = fmaf(d, a1.x, b0.z); o0.w = fmaf(d, a1.y, b0.w);
        o1.x = fmaf(d, a2.x, b1.x); o1.y = fmaf(d, a2.y, b1.y);
        o1.z = fmaf(d, a3.x, b1.z); o1.w = fmaf(d, a3.y, b1.w);
        *(float4*)(z + c * 32 + fl * 8) = o0;
        *(float4*)(z + c * 32 + fl * 8 + 4) = o1;
      }
    };

    if (sA + grp < eA)      { bf2_acc(p0.x, a0); bf2_acc(p0.y, a1); bf2_acc(p0.z, a2); bf2_acc(p0.w, a3); }
    if (sA + 16 + grp < eA) { bf2_acc(p1.x, a0); bf2_acc(p1.y, a1); bf2_acc(p1.z, a2); bf2_acc(p1.w, a3); }
    rest_row(sA + 32, eA);
    finish(c0);

    if (hasB) {
      a0 = v2f{0.f, 0.f}; a1 = v2f{0.f, 0.f}; a2 = v2f{0.f, 0.f}; a3 = v2f{0.f, 0.f};
      if (sB + grp < eB)      { bf2_acc(q0.x, a0); bf2_acc(q0.y, a1); bf2_acc(q0.z, a2); bf2_acc(q0.w, a3); }
      if (sB + 16 + grp < eB) { bf2_acc(q1.x, a0); bf2_acc(q1.y, a1); bf2_acc(q1.z, a2); bf2_acc(q1.w, a3); }
      rest_row(sB + 32, eB);
      finish(c1);
    }
  };

  if (fits) run([&](int i) { return la[i - segLo]; });
  else      run([&](int i) { return adj[i]; });
}

// ---- link decode: half-wave per label edge, shuffle reduce, fp32 out ----
__global__ __launch_bounds__(256) void k_decode(const int* __restrict__ ea,
                                                const int* __restrict__ eb,
                                                const float* __restrict__ z2,
                                                float* __restrict__ out, int EL) {
  int lane = threadIdx.x & 31;
  int e = blockIdx.x * 8 + (threadIdx.x >> 5);
  if (e >= EL) return;
  int a = ea[e], b = eb[e];
  float p = z2[a * 32 + lane] * z2[b * 32 + lane];
  p += __shfl_down(p, 16);
  p += __shfl_down(p, 8);
  p += __shfl_down(p, 4);
  p += __shfl_down(p, 2);
  p += __shfl_down(p, 1);
  if (lane == 0) out[e] = p;
}

extern "C" void kernel_launch(void* const* d_in, const int* in_sizes, int n_in,
                              void* d_out, int out_size, void* d_ws, size_t ws_size,
                              hipStream_t stream) {
  const float* x   = (const float*)d_in[0];
  const float* W1  = (const float*)d_in[1];
  const float* b1  = (const float*)d_in[2];
  const float* W2  = (const float*)d_in[3];
  const float* b2  = (const float*)d_in[4];
  const int*   ei  = (const int*)d_in[5];   // [2,E]: row=ei[0..E), col=ei[E..2E)
  const int*   eli = (const int*)d_in[6];   // [2,EL]

  const int N  = in_sizes[0] / 128;  // 100000
  const int E  = in_sizes[5] / 2;    // 3200000
  const int EL = in_sizes[6] / 2;    // 200000
  const int* row = ei;
  const int* col = ei + E;
  const int NBUCK = (N + BNODES - 1) / BNODES;   // 391
  const int NCHNK = (E + CHUNK - 1) / CHUNK;     // 782

  // workspace (~60 MB)
  char* ws = (char*)d_ws;
  size_t off = 0;
  auto take = [&](size_t bytes) { char* p = ws + off; off += (bytes + 255) & ~(size_t)255; return p; };
  float* dinv      = (float*)take((size_t)N * 4);
  int*   row_start = (int*)take((size_t)(N + 1) * 4);
  int*   btot      = (int*)take((size_t)NBUCK * 4);
  int*   bbase     = (int*)take((size_t)(NBUCK + 1) * 4);
  short* Wt1       = (short*)take((size_t)64 * 128 * 2);
  short* Wt2       = (short*)take((size_t)32 * 64 * 2);
  int*   chist     = (int*)take((size_t)NCHNK * NBUCK * 4);   // 1.22 MB
  int*   adjTmp    = (int*)take((size_t)E * 4);               // 12.8 MB
  int*   adj       = (int*)take((size_t)E * 4);               // 12.8 MB
  char*  bufH      = take((size_t)N * 64 * 2);                // g1 bf16 / g2 bf16
  short* z1b       = (short*)take((size_t)N * 64 * 2);        // relu'd, bf16
  float* z2        = (float*)take((size_t)N * 32 * 4);
  (void)ws_size; (void)n_in; (void)out_size;

  bf16*  g1 = (bf16*)bufH;
  short* g2 = (short*)bufH;   // aliases g1 (g1 dead when g2 written)

  k_prepW     <<<32, 256, 0, stream>>>(W1, W2, Wt1, Wt2);
  k_hist      <<<NCHNK, 256, 0, stream>>>(col, E, NBUCK, chist);
  k_scanbuck  <<<NBUCK, 256, 0, stream>>>(chist, NCHNK, NBUCK, btot);
  k_scanbase  <<<1, 512, 0, stream>>>(btot, NBUCK, bbase, row_start, N);
  k_binpass   <<<NCHNK, 256, 0, stream>>>(row, col, E, NBUCK, bbase, chist, adjTmp);
  k_bucketsort<<<NBUCK, 256, 0, stream>>>(bbase, adjTmp, adj, row_start, dinv, N);

  k_gemm1<<<(N + 63) / 64, 256, 0, stream>>>(x, Wt1, dinv, g1, N);
  k_gagg1<<<(N + 7) / 8, 256, 0, stream>>>(row_start, adj, dinv, (const short*)g1, b1, z1b, N, E);

  k_gemm2<<<(N + 63) / 64, 256, 0, stream>>>((const bf16*)z1b, Wt2, dinv, g2, N);
  k_gagg2<<<(N + 7) / 8, 256, 0, stream>>>(row_start, adj, dinv, g2, b2, z2, N, E);

  k_decode<<<(EL + 7) / 8, 256, 0, stream>>>(eli, eli + EL, z2, (float*)d_out, EL);
}